// Round 2
// baseline (553.446 us; speedup 1.0000x reference)
//
#include <hip/hip_runtime.h>

#define HIDDEN 1024
#define NHEADS 16
#define HDIM 64
#define WINDOW 256
#define SEQ 2048
#define BATCH 2
#define MTOK (BATCH * SEQ)
#define LN_EPS 1e-12f

typedef _Float16 f16;
typedef _Float16 f16x4 __attribute__((ext_vector_type(4)));
typedef _Float16 f16x8 __attribute__((ext_vector_type(8)));
typedef float f32x4 __attribute__((ext_vector_type(4)));

// hi/lo split: x ~= hi + lo * 2^-11, lo scaled by 2^11 to stay in fp16 normal
// range (MFMA may flush fp16 denormals; weights ~0.03 would lose their lo).
__device__ inline void split_hl(float x, f16& h, f16& l) {
    const f16 hh = (f16)x;
    h = hh;
    l = (f16)((x - (float)hh) * 2048.0f);
}

// ---------------------------------------------------------------------------
// LayerNorm fused with hi/lo fp16 split output. One block per token row.
// ---------------------------------------------------------------------------
__global__ __launch_bounds__(256) void ln_split_kernel(const float* __restrict__ X,
                                                       const float* __restrict__ g,
                                                       const float* __restrict__ be,
                                                       f16* __restrict__ XH,
                                                       f16* __restrict__ XL) {
    const int row = blockIdx.x;
    const int t = threadIdx.x;
    const float4 v = ((const float4*)(X + (size_t)row * HIDDEN))[t];
    float s = v.x + v.y + v.z + v.w;
    float s2 = v.x * v.x + v.y * v.y + v.z * v.z + v.w * v.w;
#pragma unroll
    for (int off = 1; off < 64; off <<= 1) {
        s += __shfl_xor(s, off);
        s2 += __shfl_xor(s2, off);
    }
    __shared__ float ss[4], ss2[4];
    if ((t & 63) == 0) { ss[t >> 6] = s; ss2[t >> 6] = s2; }
    __syncthreads();
    s = ss[0] + ss[1] + ss[2] + ss[3];
    s2 = ss2[0] + ss2[1] + ss2[2] + ss2[3];
    const float mu = s * (1.f / HIDDEN);
    const float var = s2 * (1.f / HIDDEN) - mu * mu;
    const float rstd = rsqrtf(var + LN_EPS);
    const float4 gv = ((const float4*)g)[t];
    const float4 bv = ((const float4*)be)[t];
    float ov[4];
    ov[0] = (v.x - mu) * rstd * gv.x + bv.x;
    ov[1] = (v.y - mu) * rstd * gv.y + bv.y;
    ov[2] = (v.z - mu) * rstd * gv.z + bv.z;
    ov[3] = (v.w - mu) * rstd * gv.w + bv.w;
    f16x4 h, l;
#pragma unroll
    for (int j = 0; j < 4; ++j) { f16 hh, ll; split_hl(ov[j], hh, ll); h[j] = hh; l[j] = ll; }
    ((f16x4*)(XH + (size_t)row * HIDDEN))[t] = h;
    ((f16x4*)(XL + (size_t)row * HIDDEN))[t] = l;
}

// ---------------------------------------------------------------------------
// f32 -> fp16 hi/lo split, 8 elems per thread.
// ---------------------------------------------------------------------------
__global__ __launch_bounds__(256) void split_kernel(const float* __restrict__ X,
                                                    f16* __restrict__ H,
                                                    f16* __restrict__ L, int n8) {
    const int i = blockIdx.x * 256 + threadIdx.x;
    if (i >= n8) return;
    const float4 a = ((const float4*)X)[2 * i];
    const float4 b = ((const float4*)X)[2 * i + 1];
    const float xs[8] = {a.x, a.y, a.z, a.w, b.x, b.y, b.z, b.w};
    f16x8 h, l;
#pragma unroll
    for (int j = 0; j < 8; ++j) { f16 hh, ll; split_hl(xs[j], hh, ll); h[j] = hh; l[j] = ll; }
    ((f16x8*)H)[i] = h;
    ((f16x8*)L)[i] = l;
}

// ---------------------------------------------------------------------------
// hi/lo fp16 MFMA GEMM-NT: C[m,n] = sum_k A[m,k]*W[n,k] + bias (+R), fp32-accurate.
// 128x128 tile, BK=32, 4 waves in 2x2, wave tile 64x64 = 4x4 frags of 16x16x32.
// C = acc1(hi*hi) + 2^-11 * acc2(lo*hi + hi*lo).
// LDS rows padded 32->40 halfs (80 B) so frag ds_read_b128 spreads banks.
// ---------------------------------------------------------------------------
template <bool RESID>
__global__ __launch_bounds__(256, 2) void gemm_f16hl(const f16* __restrict__ Ah_g,
                                                     const f16* __restrict__ Al_g,
                                                     const f16* __restrict__ Bh_g,
                                                     const f16* __restrict__ Bl_g,
                                                     const float* __restrict__ bias,
                                                     const float* __restrict__ R,
                                                     float* __restrict__ C,
                                                     int M, int N, int K) {
    __shared__ f16 Ah[128][40], Al[128][40], Bh[128][40], Bl[128][40];
    const int tid = threadIdx.x;
    const int m0 = blockIdx.x << 7, n0 = blockIdx.y << 7;
    const int w = tid >> 6, lane = tid & 63;
    const int wr = w >> 1, wc = w & 1;            // wave grid 2x2
    const int lr = lane & 15, lk = lane >> 4;     // frag row/col + k-block
    const f32x4 z = {0.f, 0.f, 0.f, 0.f};
    f32x4 acc1[4][4], acc2[4][4];
#pragma unroll
    for (int i = 0; i < 4; ++i)
#pragma unroll
        for (int j = 0; j < 4; ++j) { acc1[i][j] = z; acc2[i][j] = z; }

    for (int k0 = 0; k0 < K; k0 += 32) {
        __syncthreads();
#pragma unroll
        for (int q = 0; q < 2; ++q) {
            const int idx = (q << 8) + tid;       // 0..511
            const int r = idx >> 2, c = idx & 3;  // row, 8-half group
            const size_t ga = (size_t)(m0 + r) * K + k0 + (c << 3);
            *(f16x8*)&Ah[r][c << 3] = *(const f16x8*)(Ah_g + ga);
            *(f16x8*)&Al[r][c << 3] = *(const f16x8*)(Al_g + ga);
            const size_t gb = (size_t)(n0 + r) * K + k0 + (c << 3);
            *(f16x8*)&Bh[r][c << 3] = *(const f16x8*)(Bh_g + gb);
            *(f16x8*)&Bl[r][c << 3] = *(const f16x8*)(Bl_g + gb);
        }
        __syncthreads();
        f16x8 bh[4], bl[4];
#pragma unroll
        for (int j = 0; j < 4; ++j) {
            bh[j] = *(const f16x8*)&Bh[(wc << 6) + (j << 4) + lr][lk << 3];
            bl[j] = *(const f16x8*)&Bl[(wc << 6) + (j << 4) + lr][lk << 3];
        }
#pragma unroll
        for (int i = 0; i < 4; ++i) {
            const f16x8 ah = *(const f16x8*)&Ah[(wr << 6) + (i << 4) + lr][lk << 3];
            const f16x8 al = *(const f16x8*)&Al[(wr << 6) + (i << 4) + lr][lk << 3];
#pragma unroll
            for (int j = 0; j < 4; ++j) {
                acc1[i][j] = __builtin_amdgcn_mfma_f32_16x16x32_f16(ah, bh[j], acc1[i][j], 0, 0, 0);
                acc2[i][j] = __builtin_amdgcn_mfma_f32_16x16x32_f16(al, bh[j], acc2[i][j], 0, 0, 0);
                acc2[i][j] = __builtin_amdgcn_mfma_f32_16x16x32_f16(ah, bl[j], acc2[i][j], 0, 0, 0);
            }
        }
    }

    // C/D layout (m89/m91): col = lane&15, row = (lane>>4)*4 + reg
#pragma unroll
    for (int j = 0; j < 4; ++j) {
        const int col = n0 + (wc << 6) + (j << 4) + lr;
        const float bv = bias[col];
#pragma unroll
        for (int i = 0; i < 4; ++i) {
#pragma unroll
            for (int r = 0; r < 4; ++r) {
                const int row = m0 + (wr << 6) + (i << 4) + (lk << 2) + r;
                float val = acc1[i][j][r] + acc2[i][j][r] * (1.0f / 2048.0f) + bv;
                if (RESID) val += R[(size_t)row * N + col];
                C[(size_t)row * N + col] = val;
            }
        }
    }
}

// ---------------------------------------------------------------------------
// Flash-style causal sliding-window attention (fp32 vector).
// One block per (b, h, 64-query tile); <=5 key tiles of 64.
// Ps overlays Ks (dead during PV) -> 52 KB LDS. Masked-p bug fixed: p is
// forced to 0 where disallowed (exp2f(0)=1 pollution when a whole tile-row
// is masked and mnew is still the -1e30 sentinel).
// ---------------------------------------------------------------------------
__global__ __launch_bounds__(256, 2) void attn_kernel(const float* __restrict__ Qg,
                                                      const float* __restrict__ Kg,
                                                      const float* __restrict__ Vg,
                                                      float* __restrict__ Og) {
    __shared__ float Qs[64][68];
    __shared__ float Ks[64][68];  // doubles as Ps after QK^T
    __shared__ float Vt[64][68];  // transposed: Vt[d][k]
    const int qt = blockIdx.x;
    const int bh = blockIdx.y;
    const int b = bh >> 4, h = bh & 15;
    const int q0 = qt << 6;
    const int tid = threadIdx.x;
    const int tx = tid & 15, ty = tid >> 4;
    const float* Qb = Qg + ((size_t)(b * SEQ + q0)) * HIDDEN + h * HDIM;

#pragma unroll
    for (int l = 0; l < 4; ++l) {
        const int idx = l * 256 + tid;
        const int r = idx >> 4, c4 = idx & 15;
        *(float4*)&Qs[r][c4 * 4] = *(const float4*)(Qb + (size_t)r * HIDDEN + c4 * 4);
    }

    float acc[4][4] = {};
    float mrow[4], lrow[4];
#pragma unroll
    for (int i = 0; i < 4; ++i) { mrow[i] = -1e30f; lrow[i] = 0.f; }
    const float csc = 0.18033688011112042f;  // log2(e) / sqrt(64)

    const int kt_lo = (q0 >= WINDOW) ? ((q0 - WINDOW + 1) >> 6) : 0;
    for (int kt = kt_lo; kt <= qt; ++kt) {
        const int k0 = kt << 6;
        const float* Kb = Kg + ((size_t)(b * SEQ + k0)) * HIDDEN + h * HDIM;
        const float* Vb = Vg + ((size_t)(b * SEQ + k0)) * HIDDEN + h * HDIM;
        __syncthreads();  // prev PV done with Ks(=Ps)/Vt
#pragma unroll
        for (int l = 0; l < 4; ++l) {
            const int idx = l * 256 + tid;
            const int r = idx >> 4, c4 = idx & 15;
            *(float4*)&Ks[r][c4 * 4] = *(const float4*)(Kb + (size_t)r * HIDDEN + c4 * 4);
            const float4 v = *(const float4*)(Vb + (size_t)r * HIDDEN + c4 * 4);
            Vt[c4 * 4 + 0][r] = v.x; Vt[c4 * 4 + 1][r] = v.y;
            Vt[c4 * 4 + 2][r] = v.z; Vt[c4 * 4 + 3][r] = v.w;
        }
        __syncthreads();

        // S = Q K^T; thread owns rows ty*4+i, cols tx+16*j
        float s[4][4] = {};
#pragma unroll
        for (int d4 = 0; d4 < 16; ++d4) {
            float4 qv[4], kv[4];
#pragma unroll
            for (int i = 0; i < 4; ++i) qv[i] = *(const float4*)&Qs[ty * 4 + i][d4 * 4];
#pragma unroll
            for (int j = 0; j < 4; ++j) kv[j] = *(const float4*)&Ks[tx + 16 * j][d4 * 4];
#pragma unroll
            for (int i = 0; i < 4; ++i)
#pragma unroll
                for (int j = 0; j < 4; ++j)
                    s[i][j] += qv[i].x * kv[j].x + qv[i].y * kv[j].y +
                               qv[i].z * kv[j].z + qv[i].w * kv[j].w;
        }
        __syncthreads();  // all QK^T reads of Ks done before Ps overwrite

#pragma unroll
        for (int i = 0; i < 4; ++i) {
            const int qg = q0 + ty * 4 + i;
            bool okj[4];
            float rm = -1e30f;
#pragma unroll
            for (int j = 0; j < 4; ++j) {
                const int kg = k0 + tx + 16 * j;
                okj[j] = (kg <= qg) && (kg + WINDOW > qg);
                if (!okj[j]) s[i][j] = -1e30f;
                rm = fmaxf(rm, s[i][j]);
            }
            rm = fmaxf(rm, __shfl_xor(rm, 1));
            rm = fmaxf(rm, __shfl_xor(rm, 2));
            rm = fmaxf(rm, __shfl_xor(rm, 4));
            rm = fmaxf(rm, __shfl_xor(rm, 8));
            const float mnew = fmaxf(mrow[i], rm);
            const float corr = exp2f((mrow[i] - mnew) * csc);
            float rs = 0.f;
#pragma unroll
            for (int j = 0; j < 4; ++j) {
                const float p = okj[j] ? exp2f((s[i][j] - mnew) * csc) : 0.f;
                s[i][j] = p;
                rs += p;
            }
            rs += __shfl_xor(rs, 1);
            rs += __shfl_xor(rs, 2);
            rs += __shfl_xor(rs, 4);
            rs += __shfl_xor(rs, 8);
            lrow[i] = lrow[i] * corr + rs;
            mrow[i] = mnew;
#pragma unroll
            for (int j = 0; j < 4; ++j) acc[i][j] *= corr;
#pragma unroll
            for (int j = 0; j < 4; ++j) Ks[ty * 4 + i][tx + 16 * j] = s[i][j];  // Ps
        }
        __syncthreads();

        // O += P @ V  (Vt[d][k] so this is a float4 dot over k)
#pragma unroll
        for (int k4 = 0; k4 < 16; ++k4) {
            float4 pv[4], vv[4];
#pragma unroll
            for (int i = 0; i < 4; ++i) pv[i] = *(const float4*)&Ks[ty * 4 + i][k4 * 4];
#pragma unroll
            for (int j = 0; j < 4; ++j) vv[j] = *(const float4*)&Vt[tx + 16 * j][k4 * 4];
#pragma unroll
            for (int i = 0; i < 4; ++i)
#pragma unroll
                for (int j = 0; j < 4; ++j)
                    acc[i][j] += pv[i].x * vv[j].x + pv[i].y * vv[j].y +
                                 pv[i].z * vv[j].z + pv[i].w * vv[j].w;
        }
    }

    float* Ob = Og + ((size_t)(b * SEQ + q0)) * HIDDEN + h * HDIM;
#pragma unroll
    for (int i = 0; i < 4; ++i) {
        const float inv = 1.f / lrow[i];
#pragma unroll
        for (int j = 0; j < 4; ++j)
            Ob[(size_t)(ty * 4 + i) * HIDDEN + tx + 16 * j] = acc[i][j] * inv;
    }
}

// ---------------------------------------------------------------------------
extern "C" void kernel_launch(void* const* d_in, const int* in_sizes, int n_in,
                              void* d_out, int out_size, void* d_ws, size_t ws_size,
                              hipStream_t stream) {
    const float* hs    = (const float*)d_in[0];
    const float* gamma = (const float*)d_in[1];
    const float* beta  = (const float*)d_in[2];
    const float* Wq    = (const float*)d_in[3];
    const float* bq    = (const float*)d_in[4];
    const float* Wk    = (const float*)d_in[5];
    const float* bk    = (const float*)d_in[6];
    const float* Wv    = (const float*)d_in[7];
    const float* bv    = (const float*)d_in[8];
    const float* Wo    = (const float*)d_in[9];
    const float* bo    = (const float*)d_in[10];
    float* out = (float*)d_out;

    const size_t NTOK = (size_t)MTOK * HIDDEN;   // 4M elems (x / Q / K / V / O)
    const size_t NW = (size_t)HIDDEN * HIDDEN;   // 1M elems per weight
    char* w = (char*)d_ws;
    f16* xhi = (f16*)w;                 w += NTOK * sizeof(f16);
    f16* xlo = (f16*)w;                 w += NTOK * sizeof(f16);
    f16* wqh = (f16*)w;                 w += NW * sizeof(f16);
    f16* wql = (f16*)w;                 w += NW * sizeof(f16);
    f16* wkh = (f16*)w;                 w += NW * sizeof(f16);
    f16* wkl = (f16*)w;                 w += NW * sizeof(f16);
    f16* wvh = (f16*)w;                 w += NW * sizeof(f16);
    f16* wvl = (f16*)w;                 w += NW * sizeof(f16);
    f16* woh = (f16*)w;                 w += NW * sizeof(f16);
    f16* wol = (f16*)w;                 w += NW * sizeof(f16);
    float* Qf = (float*)w;              w += NTOK * sizeof(float);
    float* Kf = (float*)w;              w += NTOK * sizeof(float);
    float* Vf = (float*)w;              w += NTOK * sizeof(float);
    float* Of = (float*)w;              w += NTOK * sizeof(float);
    f16* ohi = (f16*)w;                 w += NTOK * sizeof(f16);
    f16* olo = (f16*)w;                 w += NTOK * sizeof(f16);

    hipLaunchKernelGGL(ln_split_kernel, dim3(MTOK), dim3(256), 0, stream,
                       hs, gamma, beta, xhi, xlo);

    const int nw8 = (int)(NW / 8);
    hipLaunchKernelGGL(split_kernel, dim3(nw8 / 256), dim3(256), 0, stream, Wq, wqh, wql, nw8);
    hipLaunchKernelGGL(split_kernel, dim3(nw8 / 256), dim3(256), 0, stream, Wk, wkh, wkl, nw8);
    hipLaunchKernelGGL(split_kernel, dim3(nw8 / 256), dim3(256), 0, stream, Wv, wvh, wvl, nw8);
    hipLaunchKernelGGL(split_kernel, dim3(nw8 / 256), dim3(256), 0, stream, Wo, woh, wol, nw8);

    dim3 gg(MTOK / 128, HIDDEN / 128);
    hipLaunchKernelGGL((gemm_f16hl<false>), gg, dim3(256), 0, stream,
                       xhi, xlo, wqh, wql, bq, nullptr, Qf, MTOK, HIDDEN, HIDDEN);
    hipLaunchKernelGGL((gemm_f16hl<false>), gg, dim3(256), 0, stream,
                       xhi, xlo, wkh, wkl, bk, nullptr, Kf, MTOK, HIDDEN, HIDDEN);
    hipLaunchKernelGGL((gemm_f16hl<false>), gg, dim3(256), 0, stream,
                       xhi, xlo, wvh, wvl, bv, nullptr, Vf, MTOK, HIDDEN, HIDDEN);

    hipLaunchKernelGGL(attn_kernel, dim3(SEQ / 64, BATCH * NHEADS), dim3(256), 0, stream,
                       Qf, Kf, Vf, Of);

    const int no8 = (int)(NTOK / 8);
    hipLaunchKernelGGL(split_kernel, dim3(no8 / 256), dim3(256), 0, stream, Of, ohi, olo, no8);

    hipLaunchKernelGGL((gemm_f16hl<true>), gg, dim3(256), 0, stream,
                       ohi, olo, woh, wol, bo, hs, out, MTOK, HIDDEN, HIDDEN);
}

// Round 4
// 311.548 us; speedup vs baseline: 1.7764x; 1.7764x over previous
//
#include <hip/hip_runtime.h>

#define HIDDEN 1024
#define NHEADS 16
#define HDIM 64
#define WINDOW 256
#define SEQ 2048
#define BATCH 2
#define MTOK (BATCH * SEQ)
#define LN_EPS 1e-12f

typedef _Float16 f16;
typedef _Float16 f16x4 __attribute__((ext_vector_type(4)));
typedef _Float16 f16x8 __attribute__((ext_vector_type(8)));
typedef float f32x4 __attribute__((ext_vector_type(4)));

// hi/lo split: x ~= hi + lo * 2^-11, lo scaled by 2^11 to stay in fp16 normal
// range (MFMA flushes fp16 denormals; weights ~0.03 would lose their lo).
__device__ inline void split_hl(float x, f16& h, f16& l) {
    const f16 hh = (f16)x;
    h = hh;
    l = (f16)((x - (float)hh) * 2048.0f);
}

// ---------------------------------------------------------------------------
// LayerNorm fused with hi/lo fp16 split output. One block per token row.
// ---------------------------------------------------------------------------
__global__ __launch_bounds__(256) void ln_split_kernel(const float* __restrict__ X,
                                                       const float* __restrict__ g,
                                                       const float* __restrict__ be,
                                                       f16* __restrict__ XH,
                                                       f16* __restrict__ XL) {
    const int row = blockIdx.x;
    const int t = threadIdx.x;
    const float4 v = ((const float4*)(X + (size_t)row * HIDDEN))[t];
    float s = v.x + v.y + v.z + v.w;
    float s2 = v.x * v.x + v.y * v.y + v.z * v.z + v.w * v.w;
#pragma unroll
    for (int off = 1; off < 64; off <<= 1) {
        s += __shfl_xor(s, off);
        s2 += __shfl_xor(s2, off);
    }
    __shared__ float ss[4], ss2[4];
    if ((t & 63) == 0) { ss[t >> 6] = s; ss2[t >> 6] = s2; }
    __syncthreads();
    s = ss[0] + ss[1] + ss[2] + ss[3];
    s2 = ss2[0] + ss2[1] + ss2[2] + ss2[3];
    const float mu = s * (1.f / HIDDEN);
    const float var = s2 * (1.f / HIDDEN) - mu * mu;
    const float rstd = rsqrtf(var + LN_EPS);
    const float4 gv = ((const float4*)g)[t];
    const float4 bv = ((const float4*)be)[t];
    float ov[4];
    ov[0] = (v.x - mu) * rstd * gv.x + bv.x;
    ov[1] = (v.y - mu) * rstd * gv.y + bv.y;
    ov[2] = (v.z - mu) * rstd * gv.z + bv.z;
    ov[3] = (v.w - mu) * rstd * gv.w + bv.w;
    f16x4 h, l;
#pragma unroll
    for (int j = 0; j < 4; ++j) { f16 hh, ll; split_hl(ov[j], hh, ll); h[j] = hh; l[j] = ll; }
    ((f16x4*)(XH + (size_t)row * HIDDEN))[t] = h;
    ((f16x4*)(XL + (size_t)row * HIDDEN))[t] = l;
}

// ---------------------------------------------------------------------------
// All-4-weights f32 -> fp16 hi/lo split in one launch (blockIdx.y = tensor).
// ---------------------------------------------------------------------------
__global__ __launch_bounds__(256) void wsplit_kernel(const float* __restrict__ W0,
                                                     const float* __restrict__ W1,
                                                     const float* __restrict__ W2,
                                                     const float* __restrict__ W3,
                                                     f16* __restrict__ H0, f16* __restrict__ L0,
                                                     f16* __restrict__ H1, f16* __restrict__ L1,
                                                     f16* __restrict__ H2, f16* __restrict__ L2,
                                                     f16* __restrict__ H3, f16* __restrict__ L3) {
    const float* X = (blockIdx.y == 0) ? W0 : (blockIdx.y == 1) ? W1 : (blockIdx.y == 2) ? W2 : W3;
    f16* H = (blockIdx.y == 0) ? H0 : (blockIdx.y == 1) ? H1 : (blockIdx.y == 2) ? H2 : H3;
    f16* L = (blockIdx.y == 0) ? L0 : (blockIdx.y == 1) ? L1 : (blockIdx.y == 2) ? L2 : L3;
    const int i = blockIdx.x * 256 + threadIdx.x;  // 8 elems per thread
    const float4 a = ((const float4*)X)[2 * i];
    const float4 b = ((const float4*)X)[2 * i + 1];
    const float xs[8] = {a.x, a.y, a.z, a.w, b.x, b.y, b.z, b.w};
    f16x8 h, l;
#pragma unroll
    for (int j = 0; j < 8; ++j) { f16 hh, ll; split_hl(xs[j], hh, ll); h[j] = hh; l[j] = ll; }
    ((f16x8*)H)[i] = h;
    ((f16x8*)L)[i] = l;
}

// ---------------------------------------------------------------------------
// hi/lo fp16 MFMA GEMM-NT: C[m,n] = sum_k A[m,k]*W[n,k] + bias (+R).
// MODE 0: f32 C + residual (output projection)
// MODE 1: f16 hi/lo out in [b, h, s, d] head-major layout   (Q, K)
// MODE 2: f16 hi/lo out in [b, h, d, s] transposed layout   (V)
// ---------------------------------------------------------------------------
template <int MODE>
__global__ __launch_bounds__(256, 2) void gemm_f16hl(const f16* __restrict__ Ah_g,
                                                     const f16* __restrict__ Al_g,
                                                     const f16* __restrict__ Bh_g,
                                                     const f16* __restrict__ Bl_g,
                                                     const float* __restrict__ bias,
                                                     const float* __restrict__ R,
                                                     float* __restrict__ C,
                                                     f16* __restrict__ OH,
                                                     f16* __restrict__ OL,
                                                     int M, int N, int K) {
    __shared__ f16 Ah[128][40], Al[128][40], Bh[128][40], Bl[128][40];
    const int tid = threadIdx.x;
    const int m0 = blockIdx.x << 7, n0 = blockIdx.y << 7;
    const int w = tid >> 6, lane = tid & 63;
    const int wr = w >> 1, wc = w & 1;            // wave grid 2x2
    const int lr = lane & 15, lk = lane >> 4;     // frag row + k-group
    const f32x4 z = {0.f, 0.f, 0.f, 0.f};
    f32x4 acc1[4][4], acc2[4][4];
#pragma unroll
    for (int i = 0; i < 4; ++i)
#pragma unroll
        for (int j = 0; j < 4; ++j) { acc1[i][j] = z; acc2[i][j] = z; }

    for (int k0 = 0; k0 < K; k0 += 32) {
        __syncthreads();
#pragma unroll
        for (int q = 0; q < 2; ++q) {
            const int idx = (q << 8) + tid;       // 0..511
            const int r = idx >> 2, c = idx & 3;  // row, 8-half group
            const size_t ga = (size_t)(m0 + r) * K + k0 + (c << 3);
            *(f16x8*)&Ah[r][c << 3] = *(const f16x8*)(Ah_g + ga);
            *(f16x8*)&Al[r][c << 3] = *(const f16x8*)(Al_g + ga);
            const size_t gb = (size_t)(n0 + r) * K + k0 + (c << 3);
            *(f16x8*)&Bh[r][c << 3] = *(const f16x8*)(Bh_g + gb);
            *(f16x8*)&Bl[r][c << 3] = *(const f16x8*)(Bl_g + gb);
        }
        __syncthreads();
        f16x8 bh[4], bl[4];
#pragma unroll
        for (int j = 0; j < 4; ++j) {
            bh[j] = *(const f16x8*)&Bh[(wc << 6) + (j << 4) + lr][lk << 3];
            bl[j] = *(const f16x8*)&Bl[(wc << 6) + (j << 4) + lr][lk << 3];
        }
#pragma unroll
        for (int i = 0; i < 4; ++i) {
            const f16x8 ah = *(const f16x8*)&Ah[(wr << 6) + (i << 4) + lr][lk << 3];
            const f16x8 al = *(const f16x8*)&Al[(wr << 6) + (i << 4) + lr][lk << 3];
#pragma unroll
            for (int j = 0; j < 4; ++j) {
                acc1[i][j] = __builtin_amdgcn_mfma_f32_16x16x32_f16(ah, bh[j], acc1[i][j], 0, 0, 0);
                acc2[i][j] = __builtin_amdgcn_mfma_f32_16x16x32_f16(al, bh[j], acc2[i][j], 0, 0, 0);
                acc2[i][j] = __builtin_amdgcn_mfma_f32_16x16x32_f16(ah, bl[j], acc2[i][j], 0, 0, 0);
            }
        }
    }

    // C/D layout: col = lane&15, row = (lane>>4)*4 + reg
#pragma unroll
    for (int j = 0; j < 4; ++j) {
        const int col = n0 + (wc << 6) + (j << 4) + lr;
        const float bv = bias[col];
#pragma unroll
        for (int i = 0; i < 4; ++i) {
#pragma unroll
            for (int r = 0; r < 4; ++r) {
                const int row = m0 + (wr << 6) + (i << 4) + (lk << 2) + r;
                float val = acc1[i][j][r] + acc2[i][j][r] * (1.0f / 2048.0f) + bv;
                if (MODE == 0) {
                    val += R[(size_t)row * N + col];
                    C[(size_t)row * N + col] = val;
                } else {
                    f16 h, l;
                    split_hl(val, h, l);
                    size_t addr;
                    if (MODE == 1)  // [b, h, s, d]
                        addr = (((size_t)(row >> 11) * NHEADS + (col >> 6)) * SEQ +
                                (row & (SEQ - 1))) * HDIM + (col & (HDIM - 1));
                    else            // [b, h, d, s]
                        addr = (((size_t)(row >> 11) * NHEADS + (col >> 6)) * HDIM +
                                (col & (HDIM - 1))) * SEQ + (row & (SEQ - 1));
                    OH[addr] = h;
                    OL[addr] = l;
                }
            }
        }
    }
}

// ---------------------------------------------------------------------------
// MFMA flash attention, causal sliding window 256.
// Block = (128-query tile, bh); 4 waves, each owns 32 q-rows.
// Q,K fp16 hi/lo (exact scores); P,V fp16 hi-only (error contracted by Wo).
// K tiles of 64 keys; Q in registers; P in wave-private LDS (no barrier).
// Output written as fp16 hi/lo [m, n] — directly the O-proj GEMM A operand.
// ---------------------------------------------------------------------------
#define QT 128
__global__ __launch_bounds__(256, 2) void attn_mfma(const f16* __restrict__ Qh,
                                                    const f16* __restrict__ Ql,
                                                    const f16* __restrict__ Kh,
                                                    const f16* __restrict__ Kl,
                                                    const f16* __restrict__ Vh,
                                                    f16* __restrict__ Oh,
                                                    f16* __restrict__ Ol) {
    __shared__ f16 Ks_h[64][72];   // [k][d], pad->72 => 8 lanes/bank-quad (b128 optimum)
    __shared__ f16 Ks_l[64][72];
    __shared__ f16 Vs[64][72];     // [d][k] (pre-transposed in global)
    __shared__ f16 Ps[4][32][72];  // per-wave P[qrow][k]
    const int qt = blockIdx.x, bh = blockIdx.y;
    const int q0 = qt * QT;
    const int tid = threadIdx.x;
    const int w = tid >> 6, lane = tid & 63;
    const int lr = lane & 15, lk = lane >> 4;
    const int qbase = q0 + w * 32;
    const float csc = 0.18033688011112042f;  // log2(e)/sqrt(64)

    // Q fragments (A-operand): [qfrag][kstep]
    f16x8 qh[2][2], ql[2][2];
#pragma unroll
    for (int qf = 0; qf < 2; ++qf)
#pragma unroll
        for (int g = 0; g < 2; ++g) {
            const size_t ga = ((size_t)bh * SEQ + qbase + qf * 16 + lr) * HDIM + g * 32 + lk * 8;
            qh[qf][g] = *(const f16x8*)(Qh + ga);
            ql[qf][g] = *(const f16x8*)(Ql + ga);
        }

    const f32x4 z = {0.f, 0.f, 0.f, 0.f};
    f32x4 o1[2][4];
    float m_[2][4], l_[2][4];
#pragma unroll
    for (int qf = 0; qf < 2; ++qf)
#pragma unroll
        for (int r = 0; r < 4; ++r) { m_[qf][r] = -1e30f; l_[qf][r] = 0.f; }
#pragma unroll
    for (int qf = 0; qf < 2; ++qf)
#pragma unroll
        for (int df = 0; df < 4; ++df) o1[qf][df] = z;

    const int kt0 = (q0 >> 6) - 4;  // first tile holding any in-window key
    for (int t = 0; t < 6; ++t) {
        const int kt = kt0 + t;
        if (kt < 0) continue;
        const int k0 = kt << 6;
        __syncthreads();
#pragma unroll
        for (int rep = 0; rep < 2; ++rep) {
            const int idx = rep * 256 + tid;      // 0..511
            const int r = idx >> 3, sg = (idx & 7) << 3;
            const size_t gk = ((size_t)bh * SEQ + k0 + r) * HDIM + sg;
            *(f16x8*)&Ks_h[r][sg] = *(const f16x8*)(Kh + gk);
            *(f16x8*)&Ks_l[r][sg] = *(const f16x8*)(Kl + gk);
            const size_t gv = ((size_t)bh * HDIM + r) * SEQ + k0 + sg;
            *(f16x8*)&Vs[r][sg] = *(const f16x8*)(Vh + gv);
        }
        __syncthreads();

        // S = Q K^T (hi*hi + (lo*hi + hi*lo)/2048)
        f32x4 s1[2][4], s2[2][4];
#pragma unroll
        for (int qf = 0; qf < 2; ++qf)
#pragma unroll
            for (int kf = 0; kf < 4; ++kf) { s1[qf][kf] = z; s2[qf][kf] = z; }
#pragma unroll
        for (int g = 0; g < 2; ++g)
#pragma unroll
            for (int kf = 0; kf < 4; ++kf) {
                const f16x8 kbh = *(const f16x8*)&Ks_h[kf * 16 + lr][g * 32 + lk * 8];
                const f16x8 kbl = *(const f16x8*)&Ks_l[kf * 16 + lr][g * 32 + lk * 8];
#pragma unroll
                for (int qf = 0; qf < 2; ++qf) {
                    s1[qf][kf] = __builtin_amdgcn_mfma_f32_16x16x32_f16(qh[qf][g], kbh, s1[qf][kf], 0, 0, 0);
                    s2[qf][kf] = __builtin_amdgcn_mfma_f32_16x16x32_f16(ql[qf][g], kbh, s2[qf][kf], 0, 0, 0);
                    s2[qf][kf] = __builtin_amdgcn_mfma_f32_16x16x32_f16(qh[qf][g], kbl, s2[qf][kf], 0, 0, 0);
                }
            }

        // online softmax; C layout: col(key)=lane&15, row(q)=lk*4+r
#pragma unroll
        for (int qf = 0; qf < 2; ++qf) {
#pragma unroll
            for (int r = 0; r < 4; ++r) {
                const int qg = qbase + qf * 16 + lk * 4 + r;
                float sc[4];
                bool ok[4];
                float rm = -1e30f;
#pragma unroll
                for (int kf = 0; kf < 4; ++kf) {
                    const int kg = k0 + kf * 16 + lr;
                    sc[kf] = s1[qf][kf][r] + s2[qf][kf][r] * (1.0f / 2048.0f);
                    ok[kf] = (kg <= qg) && (kg + WINDOW > qg);
                    if (!ok[kf]) sc[kf] = -1e30f;
                    rm = fmaxf(rm, sc[kf]);
                }
                rm = fmaxf(rm, __shfl_xor(rm, 1));
                rm = fmaxf(rm, __shfl_xor(rm, 2));
                rm = fmaxf(rm, __shfl_xor(rm, 4));
                rm = fmaxf(rm, __shfl_xor(rm, 8));
                const float mnew = fmaxf(m_[qf][r], rm);
                const float corr = exp2f((m_[qf][r] - mnew) * csc);
                float rs = 0.f;
#pragma unroll
                for (int kf = 0; kf < 4; ++kf) {
                    const float p = ok[kf] ? exp2f((sc[kf] - mnew) * csc) : 0.f;
                    sc[kf] = p;
                    rs += p;
                }
                rs += __shfl_xor(rs, 1);
                rs += __shfl_xor(rs, 2);
                rs += __shfl_xor(rs, 4);
                rs += __shfl_xor(rs, 8);
                l_[qf][r] = l_[qf][r] * corr + rs;
                m_[qf][r] = mnew;
#pragma unroll
                for (int df = 0; df < 4; ++df) o1[qf][df][r] *= corr;
#pragma unroll
                for (int kf = 0; kf < 4; ++kf)
                    Ps[w][qf * 16 + lk * 4 + r][kf * 16 + lr] = (f16)sc[kf];
            }
        }
        // Ps is wave-private: no __syncthreads needed before PV.

        // O += P V   (A = P[q][k] from LDS, B = V[d][k] from LDS)
#pragma unroll
        for (int g = 0; g < 2; ++g) {
            f16x8 pa[2];
#pragma unroll
            for (int qf = 0; qf < 2; ++qf)
                pa[qf] = *(const f16x8*)&Ps[w][qf * 16 + lr][g * 32 + lk * 8];
#pragma unroll
            for (int df = 0; df < 4; ++df) {
                const f16x8 vb = *(const f16x8*)&Vs[df * 16 + lr][g * 32 + lk * 8];
#pragma unroll
                for (int qf = 0; qf < 2; ++qf)
                    o1[qf][df] = __builtin_amdgcn_mfma_f32_16x16x32_f16(pa[qf], vb, o1[qf][df], 0, 0, 0);
            }
        }
    }

    // write O as fp16 hi/lo in [m, n] layout (A-operand of the O-projection)
    const int b = bh >> 4, h = bh & 15;
#pragma unroll
    for (int qf = 0; qf < 2; ++qf) {
#pragma unroll
        for (int r = 0; r < 4; ++r) {
            const float inv = 1.f / l_[qf][r];
            const size_t mrow = (size_t)b * SEQ + qbase + qf * 16 + lk * 4 + r;
#pragma unroll
            for (int df = 0; df < 4; ++df) {
                const int col = h * HDIM + df * 16 + lr;
                f16 hh, ll;
                split_hl(o1[qf][df][r] * inv, hh, ll);
                Oh[mrow * HIDDEN + col] = hh;
                Ol[mrow * HIDDEN + col] = ll;
            }
        }
    }
}

// ---------------------------------------------------------------------------
extern "C" void kernel_launch(void* const* d_in, const int* in_sizes, int n_in,
                              void* d_out, int out_size, void* d_ws, size_t ws_size,
                              hipStream_t stream) {
    const float* hs    = (const float*)d_in[0];
    const float* gamma = (const float*)d_in[1];
    const float* beta  = (const float*)d_in[2];
    const float* Wq    = (const float*)d_in[3];
    const float* bq    = (const float*)d_in[4];
    const float* Wk    = (const float*)d_in[5];
    const float* bk    = (const float*)d_in[6];
    const float* Wv    = (const float*)d_in[7];
    const float* bv    = (const float*)d_in[8];
    const float* Wo    = (const float*)d_in[9];
    const float* bo    = (const float*)d_in[10];
    float* out = (float*)d_out;

    const size_t NTOK = (size_t)MTOK * HIDDEN;   // 4M elems
    const size_t NW = (size_t)HIDDEN * HIDDEN;   // 1M elems per weight
    char* p = (char*)d_ws;
    f16* xhi = (f16*)p;  p += NTOK * sizeof(f16);
    f16* xlo = (f16*)p;  p += NTOK * sizeof(f16);
    f16* wqh = (f16*)p;  p += NW * sizeof(f16);
    f16* wql = (f16*)p;  p += NW * sizeof(f16);
    f16* wkh = (f16*)p;  p += NW * sizeof(f16);
    f16* wkl = (f16*)p;  p += NW * sizeof(f16);
    f16* wvh = (f16*)p;  p += NW * sizeof(f16);
    f16* wvl = (f16*)p;  p += NW * sizeof(f16);
    f16* woh = (f16*)p;  p += NW * sizeof(f16);
    f16* wol = (f16*)p;  p += NW * sizeof(f16);
    f16* Qh  = (f16*)p;  p += NTOK * sizeof(f16);
    f16* Ql  = (f16*)p;  p += NTOK * sizeof(f16);
    f16* Kh  = (f16*)p;  p += NTOK * sizeof(f16);
    f16* Kl  = (f16*)p;  p += NTOK * sizeof(f16);
    f16* Vh  = (f16*)p;  p += NTOK * sizeof(f16);
    f16* Vl  = (f16*)p;  p += NTOK * sizeof(f16);
    f16* ohi = (f16*)p;  p += NTOK * sizeof(f16);
    f16* olo = (f16*)p;  p += NTOK * sizeof(f16);

    hipLaunchKernelGGL(ln_split_kernel, dim3(MTOK), dim3(256), 0, stream,
                       hs, gamma, beta, xhi, xlo);

    hipLaunchKernelGGL(wsplit_kernel, dim3((int)(NW / 8 / 256), 4), dim3(256), 0, stream,
                       Wq, Wk, Wv, Wo, wqh, wql, wkh, wkl, wvh, wvl, woh, wol);

    dim3 gg(MTOK / 128, HIDDEN / 128);
    hipLaunchKernelGGL((gemm_f16hl<1>), gg, dim3(256), 0, stream,
                       xhi, xlo, wqh, wql, bq, nullptr, nullptr, Qh, Ql, MTOK, HIDDEN, HIDDEN);
    hipLaunchKernelGGL((gemm_f16hl<1>), gg, dim3(256), 0, stream,
                       xhi, xlo, wkh, wkl, bk, nullptr, nullptr, Kh, Kl, MTOK, HIDDEN, HIDDEN);
    hipLaunchKernelGGL((gemm_f16hl<2>), gg, dim3(256), 0, stream,
                       xhi, xlo, wvh, wvl, bv, nullptr, nullptr, Vh, Vl, MTOK, HIDDEN, HIDDEN);

    hipLaunchKernelGGL(attn_mfma, dim3(SEQ / QT, BATCH * NHEADS), dim3(256), 0, stream,
                       Qh, Ql, Kh, Kl, Vh, ohi, olo);

    hipLaunchKernelGGL((gemm_f16hl<0>), gg, dim3(256), 0, stream,
                       ohi, olo, woh, wol, bo, hs, out, nullptr, nullptr, MTOK, HIDDEN, HIDDEN);
}

// Round 6
// 287.851 us; speedup vs baseline: 1.9227x; 1.0823x over previous
//
#include <hip/hip_runtime.h>

#define HIDDEN 1024
#define NHEADS 16
#define HDIM 64
#define WINDOW 256
#define SEQ 2048
#define BATCH 2
#define MTOK (BATCH * SEQ)
#define LN_EPS 1e-12f

typedef _Float16 f16;
typedef _Float16 f16x4 __attribute__((ext_vector_type(4)));
typedef _Float16 f16x8 __attribute__((ext_vector_type(8)));
typedef float f32x4 __attribute__((ext_vector_type(4)));

// hi/lo split: x ~= hi + lo * 2^-11, lo scaled by 2^11 to stay in fp16 normal
// range (MFMA flushes fp16 denormals; weights ~0.03 would lose their lo).
__device__ inline void split_hl(float x, f16& h, f16& l) {
    const f16 hh = (f16)x;
    h = hh;
    l = (f16)((x - (float)hh) * 2048.0f);
}

// ---------------------------------------------------------------------------
// LayerNorm fused with hi/lo fp16 split output. One block per token row.
// ---------------------------------------------------------------------------
__global__ __launch_bounds__(256) void ln_split_kernel(const float* __restrict__ X,
                                                       const float* __restrict__ g,
                                                       const float* __restrict__ be,
                                                       f16* __restrict__ XH,
                                                       f16* __restrict__ XL) {
    const int row = blockIdx.x;
    const int t = threadIdx.x;
    const float4 v = ((const float4*)(X + (size_t)row * HIDDEN))[t];
    float s = v.x + v.y + v.z + v.w;
    float s2 = v.x * v.x + v.y * v.y + v.z * v.z + v.w * v.w;
#pragma unroll
    for (int off = 1; off < 64; off <<= 1) {
        s += __shfl_xor(s, off);
        s2 += __shfl_xor(s2, off);
    }
    __shared__ float ss[4], ss2[4];
    if ((t & 63) == 0) { ss[t >> 6] = s; ss2[t >> 6] = s2; }
    __syncthreads();
    s = ss[0] + ss[1] + ss[2] + ss[3];
    s2 = ss2[0] + ss2[1] + ss2[2] + ss2[3];
    const float mu = s * (1.f / HIDDEN);
    const float var = s2 * (1.f / HIDDEN) - mu * mu;
    const float rstd = rsqrtf(var + LN_EPS);
    const float4 gv = ((const float4*)g)[t];
    const float4 bv = ((const float4*)be)[t];
    float ov[4];
    ov[0] = (v.x - mu) * rstd * gv.x + bv.x;
    ov[1] = (v.y - mu) * rstd * gv.y + bv.y;
    ov[2] = (v.z - mu) * rstd * gv.z + bv.z;
    ov[3] = (v.w - mu) * rstd * gv.w + bv.w;
    f16x4 h, l;
#pragma unroll
    for (int j = 0; j < 4; ++j) { f16 hh, ll; split_hl(ov[j], hh, ll); h[j] = hh; l[j] = ll; }
    ((f16x4*)(XH + (size_t)row * HIDDEN))[t] = h;
    ((f16x4*)(XL + (size_t)row * HIDDEN))[t] = l;
}

// ---------------------------------------------------------------------------
// All-4-weights f32 -> fp16 hi/lo split in one launch (blockIdx.y = tensor).
// ---------------------------------------------------------------------------
__global__ __launch_bounds__(256) void wsplit_kernel(const float* __restrict__ W0,
                                                     const float* __restrict__ W1,
                                                     const float* __restrict__ W2,
                                                     const float* __restrict__ W3,
                                                     f16* __restrict__ H0, f16* __restrict__ L0,
                                                     f16* __restrict__ H1, f16* __restrict__ L1,
                                                     f16* __restrict__ H2, f16* __restrict__ L2,
                                                     f16* __restrict__ H3, f16* __restrict__ L3) {
    const float* X = (blockIdx.y == 0) ? W0 : (blockIdx.y == 1) ? W1 : (blockIdx.y == 2) ? W2 : W3;
    f16* H = (blockIdx.y == 0) ? H0 : (blockIdx.y == 1) ? H1 : (blockIdx.y == 2) ? H2 : H3;
    f16* L = (blockIdx.y == 0) ? L0 : (blockIdx.y == 1) ? L1 : (blockIdx.y == 2) ? L2 : L3;
    const int i = blockIdx.x * 256 + threadIdx.x;  // 8 elems per thread
    const float4 a = ((const float4*)X)[2 * i];
    const float4 b = ((const float4*)X)[2 * i + 1];
    const float xs[8] = {a.x, a.y, a.z, a.w, b.x, b.y, b.z, b.w};
    f16x8 h, l;
#pragma unroll
    for (int j = 0; j < 8; ++j) { f16 hh, ll; split_hl(xs[j], hh, ll); h[j] = hh; l[j] = ll; }
    ((f16x8*)H)[i] = h;
    ((f16x8*)L)[i] = l;
}

// ---------------------------------------------------------------------------
// FUSED Q/K/V hi/lo fp16 MFMA GEMM-NT. blockIdx.z in {0,1,2} selects the
// weight/bias/output (Q, K -> [b,h,s,d]; V -> [b,h,d,s]). Same A operand for
// all z; 768 blocks = 3 blocks/CU so staging of one block overlaps MFMA of
// another (was 256 blocks = 1/CU, 9.4% occupancy, MfmaUtil 18.7%).
// Math per output is bit-identical to the previous per-GEMM launches.
// ---------------------------------------------------------------------------
__global__ __launch_bounds__(256, 2) void gemm_qkv(
        const f16* __restrict__ Ah_g, const f16* __restrict__ Al_g,
        const f16* __restrict__ Wh0, const f16* __restrict__ Wl0,
        const f16* __restrict__ Wh1, const f16* __restrict__ Wl1,
        const f16* __restrict__ Wh2, const f16* __restrict__ Wl2,
        const float* __restrict__ b0, const float* __restrict__ b1,
        const float* __restrict__ b2,
        f16* __restrict__ O0h, f16* __restrict__ O0l,
        f16* __restrict__ O1h, f16* __restrict__ O1l,
        f16* __restrict__ O2h, f16* __restrict__ O2l) {
    constexpr int K = HIDDEN;
    __shared__ f16 Ah[128][40], Al[128][40], Bh[128][40], Bl[128][40];
    const int z = blockIdx.z;  // uniform across block
    const f16* __restrict__ Bh_g = (z == 0) ? Wh0 : (z == 1) ? Wh1 : Wh2;
    const f16* __restrict__ Bl_g = (z == 0) ? Wl0 : (z == 1) ? Wl1 : Wl2;
    const float* __restrict__ bias = (z == 0) ? b0 : (z == 1) ? b1 : b2;
    f16* __restrict__ OH = (z == 0) ? O0h : (z == 1) ? O1h : O2h;
    f16* __restrict__ OL = (z == 0) ? O0l : (z == 1) ? O1l : O2l;
    const int tid = threadIdx.x;
    const int m0 = blockIdx.x << 7, n0 = blockIdx.y << 7;
    const int w = tid >> 6, lane = tid & 63;
    const int wr = w >> 1, wc = w & 1;            // wave grid 2x2
    const int lr = lane & 15, lk = lane >> 4;     // frag row + k-group
    const f32x4 zf = {0.f, 0.f, 0.f, 0.f};
    f32x4 acc1[4][4], acc2[4][4];
#pragma unroll
    for (int i = 0; i < 4; ++i)
#pragma unroll
        for (int j = 0; j < 4; ++j) { acc1[i][j] = zf; acc2[i][j] = zf; }

    for (int k0 = 0; k0 < K; k0 += 32) {
        __syncthreads();
#pragma unroll
        for (int q = 0; q < 2; ++q) {
            const int idx = (q << 8) + tid;       // 0..511
            const int r = idx >> 2, c = idx & 3;  // row, 8-half group
            const size_t ga = (size_t)(m0 + r) * K + k0 + (c << 3);
            *(f16x8*)&Ah[r][c << 3] = *(const f16x8*)(Ah_g + ga);
            *(f16x8*)&Al[r][c << 3] = *(const f16x8*)(Al_g + ga);
            const size_t gb = (size_t)(n0 + r) * K + k0 + (c << 3);
            *(f16x8*)&Bh[r][c << 3] = *(const f16x8*)(Bh_g + gb);
            *(f16x8*)&Bl[r][c << 3] = *(const f16x8*)(Bl_g + gb);
        }
        __syncthreads();
        f16x8 bh[4], bl[4];
#pragma unroll
        for (int j = 0; j < 4; ++j) {
            bh[j] = *(const f16x8*)&Bh[(wc << 6) + (j << 4) + lr][lk << 3];
            bl[j] = *(const f16x8*)&Bl[(wc << 6) + (j << 4) + lr][lk << 3];
        }
#pragma unroll
        for (int i = 0; i < 4; ++i) {
            const f16x8 ah = *(const f16x8*)&Ah[(wr << 6) + (i << 4) + lr][lk << 3];
            const f16x8 al = *(const f16x8*)&Al[(wr << 6) + (i << 4) + lr][lk << 3];
#pragma unroll
            for (int j = 0; j < 4; ++j) {
                acc1[i][j] = __builtin_amdgcn_mfma_f32_16x16x32_f16(ah, bh[j], acc1[i][j], 0, 0, 0);
                acc2[i][j] = __builtin_amdgcn_mfma_f32_16x16x32_f16(al, bh[j], acc2[i][j], 0, 0, 0);
                acc2[i][j] = __builtin_amdgcn_mfma_f32_16x16x32_f16(ah, bl[j], acc2[i][j], 0, 0, 0);
            }
        }
    }

    // C/D layout: col = lane&15, row = (lane>>4)*4 + reg
#pragma unroll
    for (int j = 0; j < 4; ++j) {
        const int col = n0 + (wc << 6) + (j << 4) + lr;
        const float bv = bias[col];
#pragma unroll
        for (int i = 0; i < 4; ++i) {
#pragma unroll
            for (int r = 0; r < 4; ++r) {
                const int row = m0 + (wr << 6) + (i << 4) + (lk << 2) + r;
                const float val = acc1[i][j][r] + acc2[i][j][r] * (1.0f / 2048.0f) + bv;
                f16 h, l;
                split_hl(val, h, l);
                size_t addr;
                if (z != 2)  // Q, K: [b, h, s, d]
                    addr = (((size_t)(row >> 11) * NHEADS + (col >> 6)) * SEQ +
                            (row & (SEQ - 1))) * HDIM + (col & (HDIM - 1));
                else         // V: [b, h, d, s]
                    addr = (((size_t)(row >> 11) * NHEADS + (col >> 6)) * HDIM +
                            (col & (HDIM - 1))) * SEQ + (row & (SEQ - 1));
                OH[addr] = h;
                OL[addr] = l;
            }
        }
    }
}

// ---------------------------------------------------------------------------
// O-projection hi/lo fp16 MFMA GEMM-NT with f32 C + residual epilogue.
// ---------------------------------------------------------------------------
__global__ __launch_bounds__(256, 2) void gemm_oproj(const f16* __restrict__ Ah_g,
                                                     const f16* __restrict__ Al_g,
                                                     const f16* __restrict__ Bh_g,
                                                     const f16* __restrict__ Bl_g,
                                                     const float* __restrict__ bias,
                                                     const float* __restrict__ R,
                                                     float* __restrict__ C) {
    constexpr int K = HIDDEN, N = HIDDEN;
    __shared__ f16 Ah[128][40], Al[128][40], Bh[128][40], Bl[128][40];
    const int tid = threadIdx.x;
    const int m0 = blockIdx.x << 7, n0 = blockIdx.y << 7;
    const int w = tid >> 6, lane = tid & 63;
    const int wr = w >> 1, wc = w & 1;
    const int lr = lane & 15, lk = lane >> 4;
    const f32x4 zf = {0.f, 0.f, 0.f, 0.f};
    f32x4 acc1[4][4], acc2[4][4];
#pragma unroll
    for (int i = 0; i < 4; ++i)
#pragma unroll
        for (int j = 0; j < 4; ++j) { acc1[i][j] = zf; acc2[i][j] = zf; }

    for (int k0 = 0; k0 < K; k0 += 32) {
        __syncthreads();
#pragma unroll
        for (int q = 0; q < 2; ++q) {
            const int idx = (q << 8) + tid;
            const int r = idx >> 2, c = idx & 3;
            const size_t ga = (size_t)(m0 + r) * K + k0 + (c << 3);
            *(f16x8*)&Ah[r][c << 3] = *(const f16x8*)(Ah_g + ga);
            *(f16x8*)&Al[r][c << 3] = *(const f16x8*)(Al_g + ga);
            const size_t gb = (size_t)(n0 + r) * K + k0 + (c << 3);
            *(f16x8*)&Bh[r][c << 3] = *(const f16x8*)(Bh_g + gb);
            *(f16x8*)&Bl[r][c << 3] = *(const f16x8*)(Bl_g + gb);
        }
        __syncthreads();
        f16x8 bh[4], bl[4];
#pragma unroll
        for (int j = 0; j < 4; ++j) {
            bh[j] = *(const f16x8*)&Bh[(wc << 6) + (j << 4) + lr][lk << 3];
            bl[j] = *(const f16x8*)&Bl[(wc << 6) + (j << 4) + lr][lk << 3];
        }
#pragma unroll
        for (int i = 0; i < 4; ++i) {
            const f16x8 ah = *(const f16x8*)&Ah[(wr << 6) + (i << 4) + lr][lk << 3];
            const f16x8 al = *(const f16x8*)&Al[(wr << 6) + (i << 4) + lr][lk << 3];
#pragma unroll
            for (int j = 0; j < 4; ++j) {
                acc1[i][j] = __builtin_amdgcn_mfma_f32_16x16x32_f16(ah, bh[j], acc1[i][j], 0, 0, 0);
                acc2[i][j] = __builtin_amdgcn_mfma_f32_16x16x32_f16(al, bh[j], acc2[i][j], 0, 0, 0);
                acc2[i][j] = __builtin_amdgcn_mfma_f32_16x16x32_f16(ah, bl[j], acc2[i][j], 0, 0, 0);
            }
        }
    }

#pragma unroll
    for (int j = 0; j < 4; ++j) {
        const int col = n0 + (wc << 6) + (j << 4) + lr;
        const float bv = bias[col];
#pragma unroll
        for (int i = 0; i < 4; ++i) {
#pragma unroll
            for (int r = 0; r < 4; ++r) {
                const int row = m0 + (wr << 6) + (i << 4) + (lk << 2) + r;
                float val = acc1[i][j][r] + acc2[i][j][r] * (1.0f / 2048.0f) + bv;
                val += R[(size_t)row * N + col];
                C[(size_t)row * N + col] = val;
            }
        }
    }
}

// ---------------------------------------------------------------------------
// MFMA flash attention, causal sliding window 256. (unchanged, verified)
// ---------------------------------------------------------------------------
#define QT 128
__global__ __launch_bounds__(256, 2) void attn_mfma(const f16* __restrict__ Qh,
                                                    const f16* __restrict__ Ql,
                                                    const f16* __restrict__ Kh,
                                                    const f16* __restrict__ Kl,
                                                    const f16* __restrict__ Vh,
                                                    f16* __restrict__ Oh,
                                                    f16* __restrict__ Ol) {
    __shared__ f16 Ks_h[64][72];   // [k][d], pad->72 => 8 lanes/bank-quad (b128 optimum)
    __shared__ f16 Ks_l[64][72];
    __shared__ f16 Vs[64][72];     // [d][k] (pre-transposed in global)
    __shared__ f16 Ps[4][32][72];  // per-wave P[qrow][k]
    const int qt = blockIdx.x, bh = blockIdx.y;
    const int q0 = qt * QT;
    const int tid = threadIdx.x;
    const int w = tid >> 6, lane = tid & 63;
    const int lr = lane & 15, lk = lane >> 4;
    const int qbase = q0 + w * 32;
    const float csc = 0.18033688011112042f;  // log2(e)/sqrt(64)

    f16x8 qh[2][2], ql[2][2];
#pragma unroll
    for (int qf = 0; qf < 2; ++qf)
#pragma unroll
        for (int g = 0; g < 2; ++g) {
            const size_t ga = ((size_t)bh * SEQ + qbase + qf * 16 + lr) * HDIM + g * 32 + lk * 8;
            qh[qf][g] = *(const f16x8*)(Qh + ga);
            ql[qf][g] = *(const f16x8*)(Ql + ga);
        }

    const f32x4 z = {0.f, 0.f, 0.f, 0.f};
    f32x4 o1[2][4];
    float m_[2][4], l_[2][4];
#pragma unroll
    for (int qf = 0; qf < 2; ++qf)
#pragma unroll
        for (int r = 0; r < 4; ++r) { m_[qf][r] = -1e30f; l_[qf][r] = 0.f; }
#pragma unroll
    for (int qf = 0; qf < 2; ++qf)
#pragma unroll
        for (int df = 0; df < 4; ++df) o1[qf][df] = z;

    const int kt0 = (q0 >> 6) - 4;
    for (int t = 0; t < 6; ++t) {
        const int kt = kt0 + t;
        if (kt < 0) continue;
        const int k0 = kt << 6;
        __syncthreads();
#pragma unroll
        for (int rep = 0; rep < 2; ++rep) {
            const int idx = rep * 256 + tid;
            const int r = idx >> 3, sg = (idx & 7) << 3;
            const size_t gk = ((size_t)bh * SEQ + k0 + r) * HDIM + sg;
            *(f16x8*)&Ks_h[r][sg] = *(const f16x8*)(Kh + gk);
            *(f16x8*)&Ks_l[r][sg] = *(const f16x8*)(Kl + gk);
            const size_t gv = ((size_t)bh * HDIM + r) * SEQ + k0 + sg;
            *(f16x8*)&Vs[r][sg] = *(const f16x8*)(Vh + gv);
        }
        __syncthreads();

        f32x4 s1[2][4], s2[2][4];
#pragma unroll
        for (int qf = 0; qf < 2; ++qf)
#pragma unroll
            for (int kf = 0; kf < 4; ++kf) { s1[qf][kf] = z; s2[qf][kf] = z; }
#pragma unroll
        for (int g = 0; g < 2; ++g)
#pragma unroll
            for (int kf = 0; kf < 4; ++kf) {
                const f16x8 kbh = *(const f16x8*)&Ks_h[kf * 16 + lr][g * 32 + lk * 8];
                const f16x8 kbl = *(const f16x8*)&Ks_l[kf * 16 + lr][g * 32 + lk * 8];
#pragma unroll
                for (int qf = 0; qf < 2; ++qf) {
                    s1[qf][kf] = __builtin_amdgcn_mfma_f32_16x16x32_f16(qh[qf][g], kbh, s1[qf][kf], 0, 0, 0);
                    s2[qf][kf] = __builtin_amdgcn_mfma_f32_16x16x32_f16(ql[qf][g], kbh, s2[qf][kf], 0, 0, 0);
                    s2[qf][kf] = __builtin_amdgcn_mfma_f32_16x16x32_f16(qh[qf][g], kbl, s2[qf][kf], 0, 0, 0);
                }
            }

#pragma unroll
        for (int qf = 0; qf < 2; ++qf) {
#pragma unroll
            for (int r = 0; r < 4; ++r) {
                const int qg = qbase + qf * 16 + lk * 4 + r;
                float sc[4];
                bool ok[4];
                float rm = -1e30f;
#pragma unroll
                for (int kf = 0; kf < 4; ++kf) {
                    const int kg = k0 + kf * 16 + lr;
                    sc[kf] = s1[qf][kf][r] + s2[qf][kf][r] * (1.0f / 2048.0f);
                    ok[kf] = (kg <= qg) && (kg + WINDOW > qg);
                    if (!ok[kf]) sc[kf] = -1e30f;
                    rm = fmaxf(rm, sc[kf]);
                }
                rm = fmaxf(rm, __shfl_xor(rm, 1));
                rm = fmaxf(rm, __shfl_xor(rm, 2));
                rm = fmaxf(rm, __shfl_xor(rm, 4));
                rm = fmaxf(rm, __shfl_xor(rm, 8));
                const float mnew = fmaxf(m_[qf][r], rm);
                const float corr = exp2f((m_[qf][r] - mnew) * csc);
                float rs = 0.f;
#pragma unroll
                for (int kf = 0; kf < 4; ++kf) {
                    const float p = ok[kf] ? exp2f((sc[kf] - mnew) * csc) : 0.f;
                    sc[kf] = p;
                    rs += p;
                }
                rs += __shfl_xor(rs, 1);
                rs += __shfl_xor(rs, 2);
                rs += __shfl_xor(rs, 4);
                rs += __shfl_xor(rs, 8);
                l_[qf][r] = l_[qf][r] * corr + rs;
                m_[qf][r] = mnew;
#pragma unroll
                for (int df = 0; df < 4; ++df) o1[qf][df][r] *= corr;
#pragma unroll
                for (int kf = 0; kf < 4; ++kf)
                    Ps[w][qf * 16 + lk * 4 + r][kf * 16 + lr] = (f16)sc[kf];
            }
        }
        // Ps is wave-private: no __syncthreads needed before PV.

#pragma unroll
        for (int g = 0; g < 2; ++g) {
            f16x8 pa[2];
#pragma unroll
            for (int qf = 0; qf < 2; ++qf)
                pa[qf] = *(const f16x8*)&Ps[w][qf * 16 + lr][g * 32 + lk * 8];
#pragma unroll
            for (int df = 0; df < 4; ++df) {
                const f16x8 vb = *(const f16x8*)&Vs[df * 16 + lr][g * 32 + lk * 8];
#pragma unroll
                for (int qf = 0; qf < 2; ++qf)
                    o1[qf][df] = __builtin_amdgcn_mfma_f32_16x16x32_f16(pa[qf], vb, o1[qf][df], 0, 0, 0);
            }
        }
    }

    const int b = bh >> 4, h = bh & 15;
#pragma unroll
    for (int qf = 0; qf < 2; ++qf) {
#pragma unroll
        for (int r = 0; r < 4; ++r) {
            const float inv = 1.f / l_[qf][r];
            const size_t mrow = (size_t)b * SEQ + qbase + qf * 16 + lk * 4 + r;
#pragma unroll
            for (int df = 0; df < 4; ++df) {
                const int col = h * HDIM + df * 16 + lr;
                f16 hh, ll;
                split_hl(o1[qf][df][r] * inv, hh, ll);
                Oh[mrow * HIDDEN + col] = hh;
                Ol[mrow * HIDDEN + col] = ll;
            }
        }
    }
}

// ---------------------------------------------------------------------------
extern "C" void kernel_launch(void* const* d_in, const int* in_sizes, int n_in,
                              void* d_out, int out_size, void* d_ws, size_t ws_size,
                              hipStream_t stream) {
    const float* hs    = (const float*)d_in[0];
    const float* gamma = (const float*)d_in[1];
    const float* beta  = (const float*)d_in[2];
    const float* Wq    = (const float*)d_in[3];
    const float* bq    = (const float*)d_in[4];
    const float* Wk    = (const float*)d_in[5];
    const float* bk    = (const float*)d_in[6];
    const float* Wv    = (const float*)d_in[7];
    const float* bv    = (const float*)d_in[8];
    const float* Wo    = (const float*)d_in[9];
    const float* bo    = (const float*)d_in[10];
    float* out = (float*)d_out;

    const size_t NTOK = (size_t)MTOK * HIDDEN;   // 4M elems
    const size_t NW = (size_t)HIDDEN * HIDDEN;   // 1M elems per weight
    char* p = (char*)d_ws;
    f16* xhi = (f16*)p;  p += NTOK * sizeof(f16);
    f16* xlo = (f16*)p;  p += NTOK * sizeof(f16);
    f16* wqh = (f16*)p;  p += NW * sizeof(f16);
    f16* wql = (f16*)p;  p += NW * sizeof(f16);
    f16* wkh = (f16*)p;  p += NW * sizeof(f16);
    f16* wkl = (f16*)p;  p += NW * sizeof(f16);
    f16* wvh = (f16*)p;  p += NW * sizeof(f16);
    f16* wvl = (f16*)p;  p += NW * sizeof(f16);
    f16* woh = (f16*)p;  p += NW * sizeof(f16);
    f16* wol = (f16*)p;  p += NW * sizeof(f16);
    f16* Qh  = (f16*)p;  p += NTOK * sizeof(f16);
    f16* Ql  = (f16*)p;  p += NTOK * sizeof(f16);
    f16* Kh  = (f16*)p;  p += NTOK * sizeof(f16);
    f16* Kl  = (f16*)p;  p += NTOK * sizeof(f16);
    f16* Vh  = (f16*)p;  p += NTOK * sizeof(f16);
    f16* Vl  = (f16*)p;  p += NTOK * sizeof(f16);
    f16* ohi = (f16*)p;  p += NTOK * sizeof(f16);
    f16* olo = (f16*)p;  p += NTOK * sizeof(f16);

    hipLaunchKernelGGL(ln_split_kernel, dim3(MTOK), dim3(256), 0, stream,
                       hs, gamma, beta, xhi, xlo);

    hipLaunchKernelGGL(wsplit_kernel, dim3((int)(NW / 8 / 256), 4), dim3(256), 0, stream,
                       Wq, Wk, Wv, Wo, wqh, wql, wkh, wkl, wvh, wvl, woh, wol);

    // Fused Q/K/V projections: grid.z selects output; 768 blocks = 3/CU.
    hipLaunchKernelGGL(gemm_qkv, dim3(MTOK / 128, HIDDEN / 128, 3), dim3(256), 0, stream,
                       xhi, xlo, wqh, wql, wkh, wkl, wvh, wvl, bq, bk, bv,
                       Qh, Ql, Kh, Kl, Vh, Vl);

    hipLaunchKernelGGL(attn_mfma, dim3(SEQ / QT, BATCH * NHEADS), dim3(256), 0, stream,
                       Qh, Ql, Kh, Kl, Vh, ohi, olo);

    hipLaunchKernelGGL(gemm_oproj, dim3(MTOK / 128, HIDDEN / 128), dim3(256), 0, stream,
                       ohi, olo, woh, wol, bo, hs, out);
}